// Round 3
// baseline (1160.489 us; speedup 1.0000x reference)
//
#include <hip/hip_runtime.h>
#include <math.h>

// Problem constants (fixed-shape harness):
constexpr int   Nn    = 8192;
constexpr int   FIN   = 256;
constexpr int   FOUT  = 64;
constexpr float ALPHA = 0.2f;       // LeakyReLU negative slope
constexpr float NEGB  = -9e15f;     // mask value (multiplied, per original module)
constexpr float WWIN  = 110.f;      // expf(v-M)==0 exactly for v < M-104.3; margin

__device__ __forceinline__ float lrelu(float x) { return x >= 0.f ? x : ALPHA * x; }

// ---------------------------------------------------------------------------
// Kernel P1: h = nodes @ W. UNCHANGED from R2 (bit-identical fmaf chain per
// output, c ascending — this exact arithmetic produced absmax 0.0 twice).
// ---------------------------------------------------------------------------
__global__ __launch_bounds__(256) void gemm_h(
    const float* __restrict__ nodes, const float* __restrict__ W,
    float* __restrict__ h) {
  __shared__ __align__(16) float ndT[64 * 68];  // [c][r], padded
  __shared__ __align__(16) float Ws[64 * 68];   // [c][k], padded
  const int t  = threadIdx.x;
  const int r0 = blockIdx.x * 64;
  const int tx = t & 15;   // k-group: cols 4*tx..4*tx+3
  const int ty = t >> 4;   // r-group: rows 4*ty..4*ty+3
  float acc[4][4] = {{0.f}};

  for (int c0 = 0; c0 < FIN; c0 += 64) {
#pragma unroll
    for (int s = 0; s < 16; ++s) {
      const int cc = (t >> 6) + 4 * s;
      Ws[cc * 68 + (t & 63)] = W[(size_t)(c0 + cc) * FOUT + (t & 63)];
    }
#pragma unroll
    for (int s = 0; s < 4; ++s) {
      const int rl = (t >> 4) + 16 * s;
      const float4 nv = *(const float4*)&nodes[(size_t)(r0 + rl) * FIN + c0 + (t & 15) * 4];
      const int cl = (t & 15) * 4;
      ndT[(cl + 0) * 68 + rl] = nv.x;
      ndT[(cl + 1) * 68 + rl] = nv.y;
      ndT[(cl + 2) * 68 + rl] = nv.z;
      ndT[(cl + 3) * 68 + rl] = nv.w;
    }
    __syncthreads();
#pragma unroll 8
    for (int cc = 0; cc < 64; ++cc) {
      const float4 a4 = *(const float4*)&ndT[cc * 68 + 4 * ty];
      const float4 b4 = *(const float4*)&Ws[cc * 68 + 4 * tx];
      const float av[4] = {a4.x, a4.y, a4.z, a4.w};
      const float bv[4] = {b4.x, b4.y, b4.z, b4.w};
#pragma unroll
      for (int ri = 0; ri < 4; ++ri)
#pragma unroll
        for (int ki = 0; ki < 4; ++ki)
          acc[ri][ki] = fmaf(av[ri], bv[ki], acc[ri][ki]);
    }
    __syncthreads();
  }
#pragma unroll
  for (int ri = 0; ri < 4; ++ri) {
    float4 o = make_float4(acc[ri][0], acc[ri][1], acc[ri][2], acc[ri][3]);
    *(float4*)&h[(size_t)(r0 + 4 * ty + ri) * FOUT + 4 * tx] = o;
  }
}

// ---------------------------------------------------------------------------
// Kernel P2: s_src/s_dst — UNCHANGED butterfly (bit-identical to passing runs).
// ---------------------------------------------------------------------------
__global__ __launch_bounds__(256) void scores_k(
    const float* __restrict__ h, const float* __restrict__ a,
    float* __restrict__ s_src, float* __restrict__ s_dst) {
  const int t = threadIdx.x;
  const int i = blockIdx.x * 4 + (t >> 6);
  const int k = t & 63;
  const float hv = h[(size_t)i * FOUT + k];
  float sa = hv * a[k];
  float sb = hv * a[FOUT + k];
#pragma unroll
  for (int off = 32; off >= 1; off >>= 1) {
    sa += __shfl_xor(sa, off, 64);
    sb += __shfl_xor(sb, off, 64);
  }
  if (k == 0) { s_src[i] = sa; s_dst[i] = sb; }
}

// ---------------------------------------------------------------------------
// Kernel S: ONE block. Extract the 64 smallest (sd, j) pairs ascending
// (index tie-break) + global max(sd). Cached per-thread local min: only the
// winning thread rescans its 32 slots each iteration.
// ---------------------------------------------------------------------------
__global__ __launch_bounds__(256) void sel_k(
    const float* __restrict__ sd, float* __restrict__ bot_v,
    int* __restrict__ bot_i, float* __restrict__ smaxp, int* __restrict__ nflag) {
  __shared__ float sv[Nn];
  __shared__ float wv[4];
  __shared__ int   wi[4];
  const int t = threadIdx.x;
  for (int q = t; q < Nn; q += 256) sv[q] = sd[q];
  __syncthreads();

  // global max of sd (for the edge upper bound)
  float mx = -INFINITY;
  for (int q = t; q < Nn; q += 256) mx = fmaxf(mx, sv[q]);
#pragma unroll
  for (int off = 32; off >= 1; off >>= 1) mx = fmaxf(mx, __shfl_xor(mx, off, 64));
  if ((t & 63) == 0) wv[t >> 6] = mx;
  __syncthreads();
  if (t == 0) {
    smaxp[0] = fmaxf(fmaxf(wv[0], wv[1]), fmaxf(wv[2], wv[3]));
    nflag[0] = 0;
  }
  __syncthreads();

  // cached per-thread (min val, min idx) over slots q == t (mod 256)
  float bv = INFINITY; int bi = 0x7FFFFFFF;
  for (int q = t; q < Nn; q += 256) { const float v = sv[q]; if (v < bv) { bv = v; bi = q; } }

  for (int it = 0; it < 64; ++it) {
    float rv = bv; int ri = bi;
#pragma unroll
    for (int off = 32; off >= 1; off >>= 1) {
      const float ov = __shfl_xor(rv, off, 64);
      const int   oi = __shfl_xor(ri, off, 64);
      if (ov < rv || (ov == rv && oi < ri)) { rv = ov; ri = oi; }
    }
    if ((t & 63) == 0) { wv[t >> 6] = rv; wi[t >> 6] = ri; }
    __syncthreads();
    float gv = wv[0]; int gi = wi[0];
#pragma unroll
    for (int u = 1; u < 4; ++u) {
      const float ov = wv[u]; const int oi = wi[u];
      if (ov < gv || (ov == gv && oi < gi)) { gv = ov; gi = oi; }
    }
    if (t == 0) { bot_v[it] = gv; bot_i[it] = gi; }
    __syncthreads();                     // all read wv/wi before next overwrite
    if ((gi & 255) == t) {               // owner: remove winner, rebuild cache
      sv[gi] = INFINITY;
      bv = INFINITY; bi = 0x7FFFFFFF;
      for (int q = t; q < Nn; q += 256) { const float v = sv[q]; if (v < bv) { bv = v; bi = q; } }
    }
  }
}

// ---------------------------------------------------------------------------
// Kernel B: one WAVE per row. Lane e probes the e-th smallest sd. Exact-fp
// guarded: survivors can only be non-edge lanes with s<0 (edges bounded by
// lrelu(ss+smax) < thr; beyond-list bounded by lane-63's value as-nonedge).
// Any guard failure -> flag row for the dense-exact cleanup kernel.
// ---------------------------------------------------------------------------
__global__ __launch_bounds__(256) void probe_k(
    const float* __restrict__ adj, const float* __restrict__ h,
    const float* __restrict__ s_src, const float* __restrict__ bot_v,
    const int* __restrict__ bot_i, const float* __restrict__ smaxp,
    float* __restrict__ out, int* __restrict__ nflag, int* __restrict__ flist) {
  __shared__ float bvs[64];
  __shared__ int   bis[64];
  __shared__ float sms;
  const int t = threadIdx.x;
  if (t < 64) { bvs[t] = bot_v[t]; bis[t] = bot_i[t]; }
  if (t == 64) sms = smaxp[0];
  __syncthreads();

  const int e = t & 63;                 // probe rank within wave / output col
  const int i = blockIdx.x * 4 + (t >> 6);
  const float ss = s_src[i];
  const int   j  = bis[e];
  const float s  = ss + bvs[e];         // reference op order: s_src + s_dst
  const float av = adj[(size_t)i * Nn + j];
  const bool  edge = av > 0.5f;
  const float tv = lrelu(s);
  const float v  = edge ? tv : tv * NEGB;   // exact reference arithmetic
  const bool  inclass = (s < 0.f);

  const unsigned long long cand = __ballot((!edge) && inclass);
  const unsigned long long endm = __ballot(!inclass);   // lanes with s >= 0

  bool flag;
  float M = 0.f, thr = 0.f;
  if (cand == 0ull) {
    flag = true;                         // no huge-positive class found
  } else {
    const int first = __ffsll(cand) - 1; // smallest sd non-edge = row max
    M   = __shfl(v, first, 64);
    thr = M - WWIN;
    const float ebound = fmaxf(ss + sms, 0.f);   // >= every edge's v (monotone)
    flag = (thr <= ebound);
    if (endm == 0ull) {                  // class may extend beyond the list
      const float tv63 = __shfl(tv, 63, 64);
      if (tv63 * NEGB >= thr) flag = true;   // beyond-list values <= this bound
    }
  }

  if (flag) {
    if (e == 0) { const int p = atomicAdd(nflag, 1); flist[p] = i; }
    return;
  }

  const unsigned long long surv = __ballot((!edge) && inclass && (v >= thr));
  const float p = expf(v - M);           // ==1.0 for first; exact 0 below M-104.3
  float acc = 0.f, L = 0.f;
  unsigned long long m = surv;           // wave-uniform
  while (m) {
    const int e2 = __ffsll(m) - 1; m &= m - 1;
    const float pe = __shfl(p, e2, 64);
    acc = fmaf(pe, h[(size_t)bis[e2] * FOUT + e], acc);
    L += pe;
  }
  out[(size_t)i * FOUT + e] = lrelu(acc / L);
}

// ---------------------------------------------------------------------------
// Kernel C: dense-exact fallback for flagged rows (expected: zero rows).
// Full-row max -> exp -> sum -> PV, fp32 throughout. 64 blocks grid-stride
// over the flagged list; exits immediately when the list is empty.
// ---------------------------------------------------------------------------
__global__ __launch_bounds__(256) void cleanup_k(
    const float* __restrict__ adj, const float* __restrict__ h,
    const float* __restrict__ s_src, const float* __restrict__ s_dst,
    float* __restrict__ out, const int* __restrict__ nflag,
    const int* __restrict__ flist) {
  __shared__ __align__(16) float pbuf[1024];
  __shared__ float red[4];
  __shared__ float oscr[256];
  const int t  = threadIdx.x;
  const int nf = nflag[0];
  for (int r = blockIdx.x; r < nf; r += 64) {
    const int i = flist[r];
    const float ss = s_src[i];
    const float4* adjr = (const float4*)(adj + (size_t)i * Nn);
    const float4* sd4  = (const float4*)s_dst;

    // pass 1: row max
    float vmax = -INFINITY;
    for (int q4 = t; q4 < Nn / 4; q4 += 256) {
      const float4 a4 = adjr[q4]; const float4 s4 = sd4[q4];
      const float avv[4] = {a4.x, a4.y, a4.z, a4.w};
      const float svv[4] = {s4.x, s4.y, s4.z, s4.w};
#pragma unroll
      for (int u = 0; u < 4; ++u) {
        float tv = ss + svv[u];
        tv = tv >= 0.f ? tv : ALPHA * tv;
        vmax = fmaxf(vmax, (avv[u] > 0.5f) ? tv : tv * NEGB);
      }
    }
#pragma unroll
    for (int off = 32; off >= 1; off >>= 1) vmax = fmaxf(vmax, __shfl_xor(vmax, off, 64));
    if ((t & 63) == 0) red[t >> 6] = vmax;
    __syncthreads();
    const float M = fmaxf(fmaxf(red[0], red[1]), fmaxf(red[2], red[3]));
    __syncthreads();

    // pass 2: exp + sum + dense PV via LDS staging
    const int g = t >> 6, k = t & 63;
    float acc = 0.f, Lacc = 0.f;
    for (int base = 0; base < Nn; base += 1024) {
      const int q4 = (base >> 2) + t;
      const float4 a4 = adjr[q4]; const float4 s4 = sd4[q4];
      const float avv[4] = {a4.x, a4.y, a4.z, a4.w};
      const float svv[4] = {s4.x, s4.y, s4.z, s4.w};
      float pv[4];
#pragma unroll
      for (int u = 0; u < 4; ++u) {
        float tv = ss + svv[u];
        tv = tv >= 0.f ? tv : ALPHA * tv;
        const float v = (avv[u] > 0.5f) ? tv : tv * NEGB;
        pv[u] = expf(v - M);
        Lacc += pv[u];
      }
      *(float4*)&pbuf[t * 4] = make_float4(pv[0], pv[1], pv[2], pv[3]);
      __syncthreads();
      for (int jj = g; jj < 1024; jj += 4)
        acc = fmaf(pbuf[jj], h[(size_t)(base + jj) * FOUT + k], acc);
      __syncthreads();
    }
#pragma unroll
    for (int off = 32; off >= 1; off >>= 1) Lacc += __shfl_xor(Lacc, off, 64);
    if ((t & 63) == 0) red[t >> 6] = Lacc;
    __syncthreads();
    const float L = (red[0] + red[1]) + (red[2] + red[3]);
    oscr[t] = acc;
    __syncthreads();
    if (t < 64)
      out[(size_t)i * FOUT + t] =
          lrelu(((oscr[t] + oscr[64 + t]) + (oscr[128 + t] + oscr[192 + t])) / L);
    __syncthreads();
  }
}

// ---------------------------------------------------------------------------
extern "C" void kernel_launch(void* const* d_in, const int* in_sizes, int n_in,
                              void* d_out, int out_size, void* d_ws, size_t ws_size,
                              hipStream_t stream) {
  const float* nodes = (const float*)d_in[0];
  const float* adj   = (const float*)d_in[1];
  const float* W     = (const float*)d_in[2];
  const float* a     = (const float*)d_in[3];
  float* out = (float*)d_out;

  // workspace: h | s_src | s_dst | bot_v[64] | smax | bot_i[64] | nflag | flist[8192]
  float* h     = (float*)d_ws;
  float* s_src = h + (size_t)Nn * FOUT;
  float* s_dst = s_src + Nn;
  float* bot_v = s_dst + Nn;
  float* smaxp = bot_v + 64;
  int*   bot_i = (int*)(smaxp + 1);
  int*   nflag = bot_i + 64;
  int*   flist = nflag + 1;

  gemm_h   <<<Nn / 64, 256, 0, stream>>>(nodes, W, h);
  scores_k <<<Nn / 4,  256, 0, stream>>>(h, a, s_src, s_dst);
  sel_k    <<<1,       256, 0, stream>>>(s_dst, bot_v, bot_i, smaxp, nflag);
  probe_k  <<<Nn / 4,  256, 0, stream>>>(adj, h, s_src, bot_v, bot_i, smaxp,
                                         out, nflag, flist);
  cleanup_k<<<64,      256, 0, stream>>>(adj, h, s_src, s_dst, out, nflag, flist);
}

// Round 4
// 385.239 us; speedup vs baseline: 3.0124x; 3.0124x over previous
//
#include <hip/hip_runtime.h>
#include <math.h>

// Problem constants (fixed-shape harness):
constexpr int   Nn    = 8192;
constexpr int   FIN   = 256;
constexpr int   FOUT  = 64;
constexpr float ALPHA = 0.2f;       // LeakyReLU negative slope
constexpr float NEGB  = -9e15f;     // mask value (multiplied, per original module)
constexpr float WWIN  = 110.f;      // expf(v-M)==0 exactly for v-M < -104.3; margin

__device__ __forceinline__ float lrelu(float x) { return x >= 0.f ? x : ALPHA * x; }

// ---------------------------------------------------------------------------
// Kernel P1: h = nodes @ W. UNCHANGED (bit-identical fmaf chain, c ascending —
// this exact arithmetic produced absmax 0.0 three times).
// ---------------------------------------------------------------------------
__global__ __launch_bounds__(256) void gemm_h(
    const float* __restrict__ nodes, const float* __restrict__ W,
    float* __restrict__ h) {
  __shared__ __align__(16) float ndT[64 * 68];  // [c][r], padded
  __shared__ __align__(16) float Ws[64 * 68];   // [c][k], padded
  const int t  = threadIdx.x;
  const int r0 = blockIdx.x * 64;
  const int tx = t & 15;   // k-group: cols 4*tx..4*tx+3
  const int ty = t >> 4;   // r-group: rows 4*ty..4*ty+3
  float acc[4][4] = {{0.f}};

  for (int c0 = 0; c0 < FIN; c0 += 64) {
#pragma unroll
    for (int s = 0; s < 16; ++s) {
      const int cc = (t >> 6) + 4 * s;
      Ws[cc * 68 + (t & 63)] = W[(size_t)(c0 + cc) * FOUT + (t & 63)];
    }
#pragma unroll
    for (int s = 0; s < 4; ++s) {
      const int rl = (t >> 4) + 16 * s;
      const float4 nv = *(const float4*)&nodes[(size_t)(r0 + rl) * FIN + c0 + (t & 15) * 4];
      const int cl = (t & 15) * 4;
      ndT[(cl + 0) * 68 + rl] = nv.x;
      ndT[(cl + 1) * 68 + rl] = nv.y;
      ndT[(cl + 2) * 68 + rl] = nv.z;
      ndT[(cl + 3) * 68 + rl] = nv.w;
    }
    __syncthreads();
#pragma unroll 8
    for (int cc = 0; cc < 64; ++cc) {
      const float4 a4 = *(const float4*)&ndT[cc * 68 + 4 * ty];
      const float4 b4 = *(const float4*)&Ws[cc * 68 + 4 * tx];
      const float av[4] = {a4.x, a4.y, a4.z, a4.w};
      const float bv[4] = {b4.x, b4.y, b4.z, b4.w};
#pragma unroll
      for (int ri = 0; ri < 4; ++ri)
#pragma unroll
        for (int ki = 0; ki < 4; ++ki)
          acc[ri][ki] = fmaf(av[ri], bv[ki], acc[ri][ki]);
    }
    __syncthreads();
  }
#pragma unroll
  for (int ri = 0; ri < 4; ++ri) {
    float4 o = make_float4(acc[ri][0], acc[ri][1], acc[ri][2], acc[ri][3]);
    *(float4*)&h[(size_t)(r0 + 4 * ty + ri) * FOUT + 4 * tx] = o;
  }
}

// ---------------------------------------------------------------------------
// Kernel P2: s_src/s_dst — UNCHANGED butterfly (bit-identical to passing runs).
// ---------------------------------------------------------------------------
__global__ __launch_bounds__(256) void scores_k(
    const float* __restrict__ h, const float* __restrict__ a,
    float* __restrict__ s_src, float* __restrict__ s_dst) {
  const int t = threadIdx.x;
  const int i = blockIdx.x * 4 + (t >> 6);
  const int k = t & 63;
  const float hv = h[(size_t)i * FOUT + k];
  float sa = hv * a[k];
  float sb = hv * a[FOUT + k];
#pragma unroll
  for (int off = 32; off >= 1; off >>= 1) {
    sa += __shfl_xor(sa, off, 64);
    sb += __shfl_xor(sb, off, 64);
  }
  if (k == 0) { s_src[i] = sa; s_dst[i] = sb; }
}

// ---------------------------------------------------------------------------
// Kernel S (rewritten): ONE block, 1024 threads. Threshold select:
//   global min m & max smax -> bucket-count sd <= m+w_k (16 widths) ->
//   largest T with count <= 128 -> atomic compact -> O(n^2) rank sort ->
//   bottom-64 ascending (index tie-break), +INF padded.
// meta[0]=smax, meta[1]=Teff (beyond-list bound base; -INF => flag all rows).
// Compaction predicate (sv <= T) is EXACTLY the beyond-list complement, so
// the monotone bound in probe_k is airtight in fp.
// ---------------------------------------------------------------------------
__global__ __launch_bounds__(1024) void sel2_k(
    const float* __restrict__ sd, float* __restrict__ bot_v,
    int* __restrict__ bot_i, float* __restrict__ meta, int* __restrict__ nflag) {
  __shared__ float sv[Nn];          // 32 KB
  __shared__ float wr[16];
  __shared__ int   cb[16];
  __shared__ float cv[192];
  __shared__ int   ci[192];
  __shared__ int   cnt;
  __shared__ float msh;
  __shared__ int   kselsh;
  const int t = threadIdx.x, wid = t >> 6, lane = t & 63;
  for (int q = t; q < Nn; q += 1024) sv[q] = sd[q];
  if (t < 16) cb[t] = 0;
  if (t == 0) cnt = 0;
  __syncthreads();

  // global min and max
  float mn = INFINITY, mx = -INFINITY;
  for (int q = t; q < Nn; q += 1024) { const float v = sv[q]; mn = fminf(mn, v); mx = fmaxf(mx, v); }
#pragma unroll
  for (int off = 32; off >= 1; off >>= 1) {
    mn = fminf(mn, __shfl_xor(mn, off, 64));
    mx = fmaxf(mx, __shfl_xor(mx, off, 64));
  }
  if (lane == 0) wr[wid] = mn;
  __syncthreads();
  if (t == 0) { float v = INFINITY; for (int u = 0; u < 16; ++u) v = fminf(v, wr[u]); msh = v; }
  __syncthreads();
  if (lane == 0) wr[wid] = mx;
  __syncthreads();
  if (t == 0) {
    float v = -INFINITY; for (int u = 0; u < 16; ++u) v = fmaxf(v, wr[u]);
    meta[0] = v; nflag[0] = 0;
  }
  __syncthreads();
  const float m = msh;

  // candidate thresholds (deterministic, identical across threads)
  float Tk[16];
#pragma unroll
  for (int k2 = 0; k2 < 16; ++k2) Tk[k2] = m + exp2f(0.5f * (float)(k2 - 10));

  // histogram: smallest k with sv <= Tk[k]
  for (int q = t; q < Nn; q += 1024) {
    const float v = sv[q];
    if (v <= Tk[15]) {
      int k2 = 0;
      while (v > Tk[k2]) ++k2;
      atomicAdd(&cb[k2], 1);
    }
  }
  __syncthreads();
  if (t == 0) {
    int cum = 0, ks = -1;
    for (int k2 = 0; k2 < 16; ++k2) {
      cum += cb[k2];
      if (cum <= 128) ks = k2; else break;
    }
    kselsh = ks;
  }
  // init bot padding (+INF so probe lanes e>=n are inert)
  if (t < 64) { bot_v[t] = INFINITY; bot_i[t] = 0; }
  __syncthreads();
  const int ksel = kselsh;
  if (ksel < 0) { if (t == 0) meta[1] = -INFINITY; return; }  // flag-all fallback
  const float T = Tk[ksel];

  // compact (same predicate as counting => count <= 128 < 192 guaranteed)
  for (int q = t; q < Nn; q += 1024) {
    if (sv[q] <= T) {
      const int p = atomicAdd(&cnt, 1);
      if (p < 192) { cv[p] = sv[q]; ci[p] = q; }
    }
  }
  __syncthreads();
  const int n = cnt;
  if (t < n) {
    const float myv = cv[t]; const int myi = ci[t];
    int r = 0;
    for (int q = 0; q < n; ++q)
      r += (cv[q] < myv || (cv[q] == myv && ci[q] < myi)) ? 1 : 0;
    if (r < 64) { bot_v[r] = myv; bot_i[r] = myi; }
    if (r == 63 && n > 64) meta[1] = myv;   // truncated list: bound = rank-63 value
  }
  if (t == 0 && n <= 64) meta[1] = T;        // full list: bound = T (strict beyond)
}

// ---------------------------------------------------------------------------
// Kernel B: one WAVE per row, probes the bottom-sd list. Guards (all exact
// fp-monotone): edges bounded by max(ss+smax,0); beyond-list bounded by
// lrelu(ss+Teff)*NEGB; no-candidate -> flag. Flagged rows -> cleanup2_k.
// ---------------------------------------------------------------------------
__global__ __launch_bounds__(256) void probe_k(
    const float* __restrict__ adj, const float* __restrict__ h,
    const float* __restrict__ s_src, const float* __restrict__ bot_v,
    const int* __restrict__ bot_i, const float* __restrict__ meta,
    float* __restrict__ out, int* __restrict__ nflag, int* __restrict__ flist) {
  __shared__ float bvs[64];
  __shared__ int   bis[64];
  __shared__ float sms, tef;
  const int t = threadIdx.x;
  if (t < 64) { bvs[t] = bot_v[t]; bis[t] = bot_i[t]; }
  if (t == 64) sms = meta[0];
  if (t == 65) tef = meta[1];
  __syncthreads();

  const int e = t & 63;                 // probe rank within wave / output col
  const int i = blockIdx.x * 4 + (t >> 6);
  const float ss = s_src[i];
  const int   j  = bis[e];
  const float s  = ss + bvs[e];         // +INF for padded lanes -> inert
  const float av = adj[(size_t)i * Nn + j];
  const bool  edge = av > 0.5f;
  const float tv = lrelu(s);
  const float v  = edge ? tv : tv * NEGB;   // exact reference arithmetic
  const bool  inclass = (s < 0.f);

  const unsigned long long cand = __ballot((!edge) && inclass);

  bool flag;
  float M = 0.f, thr = 0.f;
  if (cand == 0ull) {
    flag = true;                         // no huge-positive candidate in list
  } else {
    const int first = __ffsll(cand) - 1; // smallest-sd non-edge = row max
    M   = __shfl(v, first, 64);
    thr = M - WWIN;
    const float ebound = fmaxf(ss + sms, 0.f);     // >= every edge's v
    const float bb = lrelu(ss + tef) * NEGB;       // >= every beyond-list v
    flag = (thr <= ebound) || (bb >= thr);
  }

  if (flag) {
    if (e == 0) { const int p = atomicAdd(nflag, 1); flist[p] = i; }
    return;
  }

  const unsigned long long surv = __ballot((!edge) && inclass && (v >= thr));
  const float p = expf(v - M);           // ==1.0 for max; exact 0 below M-104.3
  float acc = 0.f, L = 0.f;
  unsigned long long msk = surv;         // wave-uniform
  while (msk) {
    const int e2 = __ffsll(msk) - 1; msk &= msk - 1;
    const float pe = __shfl(p, e2, 64);
    acc = fmaf(pe, h[(size_t)bis[e2] * FOUT + e], acc);
    L += pe;
  }
  out[(size_t)i * FOUT + e] = lrelu(acc / L);
}

// ---------------------------------------------------------------------------
// Kernel C (rewritten): dense-exact fallback, 1024 threads/block, one flagged
// row per block iteration. Streaming phases are 2 iterations of float4 each;
// PV is 16 coalesced k-groups (h row-major, lanes=cols) with ILP unroll.
// ---------------------------------------------------------------------------
__global__ __launch_bounds__(1024) void cleanup2_k(
    const float* __restrict__ adj, const float* __restrict__ h,
    const float* __restrict__ s_src, const float* __restrict__ s_dst,
    float* __restrict__ out, const int* __restrict__ nflag,
    const int* __restrict__ flist) {
  __shared__ __align__(16) float vals[Nn];   // 32 KB
  __shared__ float wr[16];
  __shared__ float osc[1024];
  __shared__ float Msh, Lsh;
  const int nf = nflag[0];
  const int t = threadIdx.x, wid = t >> 6, lane = t & 63;
  float4* vals4 = (float4*)vals;
  const float4* sd4 = (const float4*)s_dst;

  for (int b = blockIdx.x; b < nf; b += 2048) {
    const int i = flist[b];
    const float ss = s_src[i];
    const float4* adjr = (const float4*)(adj + (size_t)i * Nn);

    // phase 1: scores -> LDS, row max
    float vmax = -INFINITY;
#pragma unroll
    for (int it = 0; it < 2; ++it) {
      const int q = t + it * 1024;
      const float4 a4 = adjr[q]; const float4 s4 = sd4[q];
      const float avv[4] = {a4.x, a4.y, a4.z, a4.w};
      const float svv[4] = {s4.x, s4.y, s4.z, s4.w};
      float4 vv; float* vp = (float*)&vv;
#pragma unroll
      for (int u = 0; u < 4; ++u) {
        float tvv = ss + svv[u];
        tvv = tvv >= 0.f ? tvv : ALPHA * tvv;
        vp[u] = (avv[u] > 0.5f) ? tvv : tvv * NEGB;
        vmax = fmaxf(vmax, vp[u]);
      }
      vals4[q] = vv;
    }
#pragma unroll
    for (int off = 32; off >= 1; off >>= 1) vmax = fmaxf(vmax, __shfl_xor(vmax, off, 64));
    if (lane == 0) wr[wid] = vmax;
    __syncthreads();
    if (t == 0) { float v = -INFINITY; for (int u = 0; u < 16; ++u) v = fmaxf(v, wr[u]); Msh = v; }
    __syncthreads();
    const float M = Msh;

    // phase 2: exp in place, sum
    float ls = 0.f;
#pragma unroll
    for (int it = 0; it < 2; ++it) {
      const int q = t + it * 1024;
      float4 vv = vals4[q];
      float4 pp;
      pp.x = expf(vv.x - M); pp.y = expf(vv.y - M);
      pp.z = expf(vv.z - M); pp.w = expf(vv.w - M);
      vals4[q] = pp;
      ls += (pp.x + pp.y) + (pp.z + pp.w);
    }
#pragma unroll
    for (int off = 32; off >= 1; off >>= 1) ls += __shfl_xor(ls, off, 64);
    if (lane == 0) wr[wid] = ls;
    __syncthreads();
    if (t == 0) { float v = 0.f; for (int u = 0; u < 16; ++u) v += wr[u]; Lsh = v; }
    __syncthreads();
    const float L = Lsh;

    // phase 3: dense PV, 16 k-groups, coalesced h reads (L2-hot)
    float acc = 0.f;
#pragma unroll 8
    for (int jj = wid; jj < Nn; jj += 16)
      acc = fmaf(vals[jj], h[(size_t)jj * FOUT + lane], acc);
    osc[t] = acc;
    __syncthreads();
    if (t < 64) {
      float tot = 0.f;
#pragma unroll
      for (int u = 0; u < 16; ++u) tot += osc[u * 64 + t];
      out[(size_t)i * FOUT + t] = lrelu(tot / L);
    }
    __syncthreads();   // protect vals/osc before next row
  }
}

// ---------------------------------------------------------------------------
extern "C" void kernel_launch(void* const* d_in, const int* in_sizes, int n_in,
                              void* d_out, int out_size, void* d_ws, size_t ws_size,
                              hipStream_t stream) {
  const float* nodes = (const float*)d_in[0];
  const float* adj   = (const float*)d_in[1];
  const float* W     = (const float*)d_in[2];
  const float* a     = (const float*)d_in[3];
  float* out = (float*)d_out;

  // workspace: h | s_src | s_dst | bot_v[64] | meta[4] | bot_i[64] | nflag | flist[8192]
  float* h     = (float*)d_ws;
  float* s_src = h + (size_t)Nn * FOUT;
  float* s_dst = s_src + Nn;
  float* bot_v = s_dst + Nn;
  float* meta  = bot_v + 64;
  int*   bot_i = (int*)(meta + 4);
  int*   nflag = bot_i + 64;
  int*   flist = nflag + 1;

  gemm_h    <<<Nn / 64, 256,  0, stream>>>(nodes, W, h);
  scores_k  <<<Nn / 4,  256,  0, stream>>>(h, a, s_src, s_dst);
  sel2_k    <<<1,       1024, 0, stream>>>(s_dst, bot_v, bot_i, meta, nflag);
  probe_k   <<<Nn / 4,  256,  0, stream>>>(adj, h, s_src, bot_v, bot_i, meta,
                                           out, nflag, flist);
  cleanup2_k<<<2048,    1024, 0, stream>>>(adj, h, s_src, s_dst, out, nflag, flist);
}